// Round 12
// baseline (31.698 us; speedup 1.0000x reference)
//
#include <hip/hip_runtime.h>
#include <math.h>

#define BB 32
#define MM 256
#define H2 32
#define NOUT 8

typedef float v2f __attribute__((ext_vector_type(2)));

// sinh(t) up to sign (caller squares it). Series keeps relative accuracy for
// small t; exp formula for |t| >= 0.5.
__device__ __forceinline__ float sinh_mag(float t) {
    float a  = fabsf(t);
    float e  = __expf(a);
    float big = 0.5f * (e - __builtin_amdgcn_rcpf(e));
    float t2 = t * t;
    float small = t + t * t2 * (1.0f/6.0f + t2 * (1.0f/120.0f));
    return (a < 0.5f) ? small : big;
}

// sin(t) up to sign (caller squares it). Series for small t avoids the
// cos-cancellation region; hw sin elsewhere.
__device__ __forceinline__ float sin_mag(float t) {
    float a  = fabsf(t);
    float t2 = t * t;
    float small = t + t * t2 * (-1.0f/6.0f + t2 * (1.0f/120.0f));
    float big = __sinf(t);
    return (a < 0.5f) ? small : big;
}

__global__ __launch_bounds__(256) void interaction_kernel(
    const float* __restrict__ x, const int* __restrict__ mask,
    const float* __restrict__ W1, const float* __restrict__ b1,
    const float* __restrict__ W2, const float* __restrict__ b2,
    float* __restrict__ out)
{
    // XCD-chunked swizzle: 8192 blocks, 8 XCDs
    const int bid = blockIdx.x;
    const int nb  = (bid & 7) * 1024 + (bid >> 3);
    const int b   = nb >> 8;
    const int i   = nb & 255;
    const int t   = threadIdx.x;      // j index

    const int mi = mask[b * MM + i];  // block-uniform
    if (mi == 0) return;              // zeros handled by hipMemsetAsync

    float* op = out + ((size_t)(b * NOUT)) * (MM * MM) + (size_t)i * MM + t;
    const int PSTRIDE = MM * MM;

    // i-side (block-uniform -> scalar loads)
    const float eta_i = x[(b * MM + i) * 3 + 0];
    const float phi_i = x[(b * MM + i) * 3 + 1];
    const float lpt_i = x[(b * MM + i) * 3 + 2];

    // j-side per-thread
    const float eta_j = x[(b * MM + t) * 3 + 0];
    const float phi_j = x[(b * MM + t) * 3 + 1];
    const float lpt_j = x[(b * MM + t) * 3 + 2];
    const float mf    = mask[b * MM + t] ? 1.f : 0.f;

    const float dx  = eta_i - eta_j;
    const float dy  = phi_i - phi_j;
    const float dr2 = dx * dx + dy * dy;

    const float L   = (dr2 > 0.f) ? 0.5f * __logf(dr2) : 0.f;
    const float fdr = L;
    const float fkt = (dr2 > 0.f) ? fminf(lpt_i, lpt_j) + L : 0.f;

    // cosh(dx) - cos(dy) = 2*(sinh^2(dx/2) + sin^2(dy/2)) (cancellation-free)
    const float sh = sinh_mag(0.5f * dx);
    const float sn = sin_mag(0.5f * dy);
    const float c  = 2.0f * (sh * sh + sn * sn);
    const float fmass = (c > 0.f) ? __logf(2.0f * c) + lpt_i + lpt_j : 0.f;

    // ---- packed-f32 MLP (v_pk_fma_f32): layer 1 packed over k-pairs ----
    const v2f fmass2 = (v2f)(fmass);
    const v2f fdr2   = (v2f)(fdr);
    const v2f fkt2   = (v2f)(fkt);
    const v2f zero2  = (v2f)(0.f);

    v2f z2[H2 / 2];
    #pragma unroll
    for (int m = 0; m < H2 / 2; ++m) {
        v2f w0, w1, w2, bb;
        w0.x = W1[(2 * m) * 3 + 0]; w0.y = W1[(2 * m + 1) * 3 + 0];
        w1.x = W1[(2 * m) * 3 + 1]; w1.y = W1[(2 * m + 1) * 3 + 1];
        w2.x = W1[(2 * m) * 3 + 2]; w2.y = W1[(2 * m + 1) * 3 + 2];
        bb   = *(const v2f*)(b1 + 2 * m);
        v2f tt = bb;
        tt = __builtin_elementwise_fma(fmass2, w0, tt);
        tt = __builtin_elementwise_fma(fdr2,   w1, tt);
        tt = __builtin_elementwise_fma(fkt2,   w2, tt);
        // leaky_relu == max(t,0) + 0.01*min(t,0) (exact)
        z2[m] = __builtin_elementwise_fma(
                    (v2f)(0.01f), __builtin_elementwise_min(tt, zero2),
                    __builtin_elementwise_max(tt, zero2));
    }

    v2f opk[NOUT];
    #pragma unroll
    for (int p = 0; p < NOUT; ++p) { opk[p].x = b2[p]; opk[p].y = 0.f; }

    #pragma unroll
    for (int m = 0; m < H2 / 2; ++m) {
        #pragma unroll
        for (int p = 0; p < NOUT; ++p) {
            const v2f wv = *(const v2f*)(W2 + p * H2 + 2 * m);
            opk[p] = __builtin_elementwise_fma(z2[m], wv, opk[p]);
        }
    }

    #pragma unroll
    for (int p = 0; p < NOUT; ++p)
        __builtin_nontemporal_store((opk[p].x + opk[p].y) * mf, op + p * PSTRIDE);
}

extern "C" void kernel_launch(void* const* d_in, const int* in_sizes, int n_in,
                              void* d_out, int out_size, void* d_ws, size_t ws_size,
                              hipStream_t stream) {
    const float* x    = (const float*)d_in[0];
    const int*   mask = (const int*)d_in[1];
    const float* W1   = (const float*)d_in[2];
    const float* b1   = (const float*)d_in[3];
    const float* W2   = (const float*)d_in[4];
    const float* b2   = (const float*)d_in[5];
    float* out = (float*)d_out;

    // zero rows (mi==0 or masked j's) via the runtime's tuned fill path;
    // kernel then writes only active rows (~half the bytes).
    hipMemsetAsync(out, 0, (size_t)out_size * sizeof(float), stream);

    dim3 grid(BB * MM);
    dim3 block(MM);
    interaction_kernel<<<grid, block, 0, stream>>>(x, mask, W1, b1, W2, b2, out);
}